// Round 11
// baseline (290.674 us; speedup 1.0000x reference)
//
#include <hip/hip_runtime.h>
#include <hip/hip_bf16.h>
#include <math.h>

typedef __bf16 bf16_t;
typedef __bf16 bf16x8 __attribute__((ext_vector_type(8)));
typedef __bf16 bf16x4 __attribute__((ext_vector_type(4)));
typedef float f32x4 __attribute__((ext_vector_type(4)));

#define MFMA_B16(a, b, c) __builtin_amdgcn_mfma_f32_16x16x32_bf16((a), (b), (c), 0, 0, 0)

static constexpr int Bn = 2, Sn = 2048, Dn = 768, Hn = 12, Fn = 3072;
static constexpr int NTOK = Bn * Sn;  // 4096
// 0.125 (1/sqrt(dk)) * log2(e): folded into Q so softmax uses exp2
#define QSCALE 0.18033688011112042f

// async global->LDS, 16B per lane; lds base wave-uniform (HW adds lane*16).
// R4-R8 evidence: gl_lds16 staging never spills; manual VGPR staging always does.
__device__ __forceinline__ void gl_lds16(const bf16_t* g, void* lds) {
  __builtin_amdgcn_global_load_lds(
      (const __attribute__((address_space(1))) uint32_t*)g,
      (__attribute__((address_space(3))) uint32_t*)lds, 16, 0, 0);
}

// ---------------- prep: weight transposes + bias concat + LN1, one dispatch ----------------
__global__ __launch_bounds__(256) void k_prep(const float* __restrict__ wq, const float* __restrict__ wk,
                                              const float* __restrict__ wv, const float* __restrict__ wo,
                                              const float* __restrict__ w1, const float* __restrict__ w2,
                                              const float* __restrict__ bq, const float* __restrict__ bk,
                                              const float* __restrict__ bv,
                                              bf16_t* __restrict__ WqkvT, bf16_t* __restrict__ WoT,
                                              bf16_t* __restrict__ W1T, bf16_t* __restrict__ W2T,
                                              float* __restrict__ QKVB,
                                              const float* __restrict__ x, const float* __restrict__ ln_g,
                                              const float* __restrict__ ln_b, bf16_t* __restrict__ Hbuf) {
  int t = blockIdx.x;
  int tid = threadIdx.x;
  if (t >= 1729) {  // --- LayerNorm branch ---
    int tok = t - 1729;
    const float* xr = x + (size_t)tok * Dn;
    float v0 = xr[tid], v1 = xr[tid + 256], v2 = xr[tid + 512];
    float s = v0 + v1 + v2;
    float ss = v0 * v0 + v1 * v1 + v2 * v2;
    __shared__ float red[8];
#pragma unroll
    for (int off = 32; off > 0; off >>= 1) {
      s += __shfl_down(s, off);
      ss += __shfl_down(ss, off);
    }
    int w = tid >> 6, l = tid & 63;
    if (l == 0) { red[w] = s; red[4 + w] = ss; }
    __syncthreads();
    s = red[0] + red[1] + red[2] + red[3];
    ss = red[4] + red[5] + red[6] + red[7];
    float mu = s * (1.0f / Dn);
    float var = ss * (1.0f / Dn) - mu * mu;
    float rstd = rsqrtf(var + 1e-5f);
    bf16_t* orow = Hbuf + (size_t)tok * Dn;
    orow[tid]       = (bf16_t)((v0 - mu) * rstd * ln_g[tid]       + ln_b[tid]);
    orow[tid + 256] = (bf16_t)((v1 - mu) * rstd * ln_g[tid + 256] + ln_b[tid + 256]);
    orow[tid + 512] = (bf16_t)((v2 - mu) * rstd * ln_g[tid + 512] + ln_b[tid + 512]);
    return;
  }
  if (t == 1728) {
    for (int i = tid; i < 2304; i += 256)
      QKVB[i] = i < 768 ? bq[i] : (i < 1536 ? bk[i - 768] : bv[i - 1536]);
    return;
  }
  __shared__ float T[64][65];
  const float* src;
  bf16_t* dst;
  int P, Q, tp, tq;
  if (t < 432) {
    int pb = t / 12; tp = t - pb * 12; tq = 0;
    int proj = pb / 12, head = pb - proj * 12;
    src = (proj == 0 ? wq : proj == 1 ? wk : wv) + (size_t)head * 768 * 64;
    dst = WqkvT + (size_t)proj * 589824 + (size_t)head * 64 * 768;
    P = 768; Q = 64;
  } else if (t < 576) {
    int u = t - 432; tp = u / 12; tq = u - tp * 12;
    src = wo; dst = WoT; P = 768; Q = 768;
  } else if (t < 1152) {
    int u = t - 576; tp = u / 48; tq = u - tp * 48;
    src = w1; dst = W1T; P = 768; Q = 3072;
  } else {
    int u = t - 1152; tp = u / 12; tq = u - tp * 12;
    src = w2; dst = W2T; P = 3072; Q = 768;
  }
  int j = tid & 63, i0 = tid >> 6;
#pragma unroll
  for (int i = i0; i < 64; i += 4)
    T[i][j] = src[(size_t)(tp * 64 + i) * Q + tq * 64 + j];
  __syncthreads();
#pragma unroll
  for (int i = i0; i < 64; i += 4)
    dst[(size_t)(tq * 64 + i) * P + tp * 64 + j] = (bf16_t)T[j][i];
}

// ---------------- LayerNorm over D=768, one token per block (LN2) ----------------
__global__ __launch_bounds__(256) void k_layernorm(const float* __restrict__ x,
                                                   const float* __restrict__ g,
                                                   const float* __restrict__ bb,
                                                   bf16_t* __restrict__ out) {
  int t = blockIdx.x, tid = threadIdx.x;
  const float* xr = x + (size_t)t * Dn;
  float v0 = xr[tid], v1 = xr[tid + 256], v2 = xr[tid + 512];
  float s = v0 + v1 + v2;
  float ss = v0 * v0 + v1 * v1 + v2 * v2;
  __shared__ float red[8];
#pragma unroll
  for (int off = 32; off > 0; off >>= 1) {
    s += __shfl_down(s, off);
    ss += __shfl_down(ss, off);
  }
  int w = tid >> 6, l = tid & 63;
  if (l == 0) { red[w] = s; red[4 + w] = ss; }
  __syncthreads();
  s = red[0] + red[1] + red[2] + red[3];
  ss = red[4] + red[5] + red[6] + red[7];
  float mu = s * (1.0f / Dn);
  float var = ss * (1.0f / Dn) - mu * mu;
  float rstd = rsqrtf(var + 1e-5f);
  bf16_t* orow = out + (size_t)t * Dn;
  orow[tid]       = (bf16_t)((v0 - mu) * rstd * g[tid]       + bb[tid]);
  orow[tid + 256] = (bf16_t)((v1 - mu) * rstd * g[tid + 256] + bb[tid + 256]);
  orow[tid + 512] = (bf16_t)((v2 - mu) * rstd * g[tid + 512] + bb[tid + 512]);
}

// ---------------- bf16 MFMA GEMM, gl_lds16 staging, BK in {32,64,128} as stacked halves ----------------
enum { EPI_QK = 0, EPI_VT = 1, EPI_Y = 2, EPI_GELU = 3, EPI_OUT = 4 };

template <int MT, int NT, int BK, int EPI, int OCC, int SWZ>
__global__ __launch_bounds__(256, OCC) void k_gemm(const bf16_t* __restrict__ A,
                                                   const bf16_t* __restrict__ Bt,
                                                   int N, int K,
                                                   const float* __restrict__ bias,
                                                   const float* __restrict__ resid,
                                                   void* __restrict__ out0,
                                                   void* __restrict__ out1) {
  constexpr int MI = MT / 32, NI = NT / 32;
  constexpr int WROWS = MT / 2, WCOLS = NT / 2;
  constexpr int KS = BK / 32;                 // MFMA k-steps (= LDS halves) per round
  __shared__ __align__(16) bf16_t As[2][MT * BK];
  __shared__ __align__(16) bf16_t Bs[2][NT * BK];
  const int tid = threadIdx.x;
  const int w = tid >> 6, l = tid & 63;
  const int wm = w >> 1, wn = w & 1;
  const int mloc = l & 15, kblk = l >> 4;
  int bx = blockIdx.x, by = blockIdx.y;
  if constexpr (SWZ) {  // requires gridDim.y % 8 == 0
    int lin = by * gridDim.x + bx;
    int xcd = lin & 7, s = lin >> 3;
    by = xcd * (gridDim.y >> 3) + s / gridDim.x;
    bx = s - (s / gridDim.x) * gridDim.x;
  }

  f32x4 acc[MI][NI];
#pragma unroll
  for (int i = 0; i < MI; ++i)
#pragma unroll
    for (int j = 0; j < NI; ++j) acc[i][j] = f32x4{0.f, 0.f, 0.f, 0.f};

  const bf16_t* gA = A + (size_t)(by * MT + (tid >> 2)) * K + (tid & 3) * 8;
  const bf16_t* gB = Bt + (size_t)(bx * NT + (tid >> 2)) * K + (tid & 3) * 8;
  const int nk = K / BK;

  auto stage = [&](int kt, int buf) {
#pragma unroll
    for (int h = 0; h < KS; ++h) {
#pragma unroll
      for (int rb = 0; rb < MT / 64; ++rb)
        gl_lds16(gA + (size_t)rb * 64 * K + kt * BK + h * 32,
                 (char*)&As[buf][0] + h * (MT * 64) + rb * 4096 + w * 1024);
#pragma unroll
      for (int rb = 0; rb < NT / 64; ++rb)
        gl_lds16(gB + (size_t)rb * 64 * K + kt * BK + h * 32,
                 (char*)&Bs[buf][0] + h * (NT * 64) + rb * 4096 + w * 1024);
    }
  };

  stage(0, 0);
  for (int kt = 0; kt < nk; ++kt) {
    __syncthreads();
    if (kt + 1 < nk) stage(kt + 1, (kt + 1) & 1);
    const bf16_t* Ab = &As[kt & 1][0];
    const bf16_t* Bb = &Bs[kt & 1][0];
    bf16x8 af[MI][KS], bfv[NI][KS];
#pragma unroll
    for (int mi = 0; mi < MI; ++mi)
#pragma unroll
      for (int ks = 0; ks < KS; ++ks)
        af[mi][ks] = *(const bf16x8*)&Ab[ks * (MT * 32) + (wm * WROWS + mi * 16 + mloc) * 32 + kblk * 8];
#pragma unroll
    for (int ni = 0; ni < NI; ++ni)
#pragma unroll
      for (int ks = 0; ks < KS; ++ks)
        bfv[ni][ks] = *(const bf16x8*)&Bb[ks * (NT * 32) + (wn * WCOLS + ni * 16 + mloc) * 32 + kblk * 8];
#pragma unroll
    for (int ks = 0; ks < KS; ++ks)
#pragma unroll
      for (int mi = 0; mi < MI; ++mi)
#pragma unroll
        for (int ni = 0; ni < NI; ++ni)
          acc[mi][ni] = MFMA_B16(af[mi][ks], bfv[ni][ks], acc[mi][ni]);
  }

  const int gmb = by * MT + wm * WROWS + kblk * 4;
  const int gnb = bx * NT + wn * WCOLS + mloc;
  if constexpr (EPI == EPI_QK) {
    constexpr int TPP = 768 / NT;  // n-tiles per projection
    const int proj = bx / TPP;     // 0 = Q (scaled), 1 = K
#pragma unroll
    for (int mi = 0; mi < MI; ++mi)
#pragma unroll
      for (int ni = 0; ni < NI; ++ni) {
        int gn = gnb + ni * 16;
        float bv = bias[gn];
        int gm0 = gmb + mi * 16;
        if (proj == 0) {
          bf16_t* dst = (bf16_t*)out0;
#pragma unroll
          for (int r = 0; r < 4; ++r)
            dst[(size_t)(gm0 + r) * 768 + gn] = (bf16_t)((acc[mi][ni][r] + bv) * QSCALE);
        } else {
          bf16_t* dst = (bf16_t*)out1;
#pragma unroll
          for (int r = 0; r < 4; ++r)
            dst[(size_t)(gm0 + r) * 768 + (gn - 768)] = (bf16_t)(acc[mi][ni][r] + bv);
        }
      }
  } else if constexpr (EPI == EPI_VT) {
    bf16_t* dst = (bf16_t*)out0;
#pragma unroll
    for (int mi = 0; mi < MI; ++mi)
#pragma unroll
      for (int ni = 0; ni < NI; ++ni) {
        int gn = gnb + ni * 16;
        int bq = gn >> 11, sq = gn & 2047;
#pragma unroll
        for (int r = 0; r < 4; ++r) {
          int gm = gmb + mi * 16 + r;
          int hq = gm >> 6, dk = gm & 63;
          dst[((size_t)(bq * Hn + hq) * 64 + dk) * Sn + sq] = (bf16_t)(acc[mi][ni][r] + bias[gm]);
        }
      }
  } else if constexpr (EPI == EPI_GELU) {
    bf16_t* dst = (bf16_t*)out0;
#pragma unroll
    for (int mi = 0; mi < MI; ++mi)
#pragma unroll
      for (int ni = 0; ni < NI; ++ni) {
        int gn = gnb + ni * 16;
        float bv = bias[gn];
#pragma unroll
        for (int r = 0; r < 4; ++r) {
          int gm = gmb + mi * 16 + r;
          float t = acc[mi][ni][r] + bv;
          float ge = 0.5f * t * (1.0f + erff(t * 0.70710678118654752f));
          dst[(size_t)gm * N + gn] = (bf16_t)ge;
        }
      }
  } else {  // EPI_Y / EPI_OUT: + bias + residual, fp32 out
    float* dst = (float*)out0;
#pragma unroll
    for (int mi = 0; mi < MI; ++mi)
#pragma unroll
      for (int ni = 0; ni < NI; ++ni) {
        int gn = gnb + ni * 16;
        float bv = bias[gn];
#pragma unroll
        for (int r = 0; r < 4; ++r) {
          int gm = gmb + mi * 16 + r;
          dst[(size_t)gm * N + gn] = acc[mi][ni][r] + bv + resid[(size_t)gm * N + gn];
        }
      }
  }
}

// ---------------- flash attention: 256 threads, 128 q-rows/block, 2 q-subtiles per wave ----------------
// Each wave computes 32 q-columns (two B-fragments) so every K/V LDS fragment read
// feeds 2 MFMAs — halves per-CU LDS read traffic (the R10 bottleneck: 32 b128/wave-iter
// ~= 384 cyc > MFMA/VALU). Grid (16,24)=384 blocks, LDS 64 KB, OCC=2: single pass.
// Fixed-max softmax (scores bounded, exp2 safe); σ-permuted K rows keep the PV
// B-operand (P^T) in each lane's own registers; V consumed as V^T (pre-transposed).
__global__ __launch_bounds__(256, 2) void k_attn(const bf16_t* __restrict__ Q,
                                                 const bf16_t* __restrict__ K,
                                                 const bf16_t* __restrict__ VT,
                                                 bf16_t* __restrict__ O) {
  __shared__ __align__(16) bf16_t Ks[2][8192];  // [buf][dk-half(4096 el)][128 rows σ][32]
  __shared__ __align__(16) bf16_t Vs[2][8192];  // [buf][kv-chunk(2048 el)][64 dk][32]
  const int tid = threadIdx.x, w = tid >> 6, l = tid & 63;
  const int mloc = l & 15, kblk = l >> 4;
  const int bh = blockIdx.y, b = bh / Hn, h = bh - b * Hn;
  const int q0 = blockIdx.x * 128;

  // two q-subtiles per wave: qa = q0 + w*32 + mloc, qb = qa + 16
  const size_t qoffA = (size_t)(b * Sn + q0 + w * 32 + mloc) * Dn + h * 64 + kblk * 8;
  const bf16x8 qfa0 = *(const bf16x8*)(Q + qoffA);
  const bf16x8 qfa1 = *(const bf16x8*)(Q + qoffA + 32);
  const bf16x8 qfb0 = *(const bf16x8*)(Q + qoffA + (size_t)16 * Dn);
  const bf16x8 qfb1 = *(const bf16x8*)(Q + qoffA + (size_t)16 * Dn + 32);

  bf16x8 ones;
#pragma unroll
  for (int j = 0; j < 8; ++j) ones[j] = (bf16_t)1.0f;

  // K staging: thread covers σ-row of tq in [0,64); rb adds +64 (σ passes bit 6 through)
  const int tq = tid >> 2, q4 = tid & 3;
  const int s0 = (tq & 0x20) | ((tq & 0x0C) << 1) | ((tq & 0x10) >> 2) | (tq & 3);
  const bf16_t* Kg = K + (size_t)(b * Sn + s0) * Dn + h * 64 + q4 * 8;
  // V staging: wave w owns kv-chunk w; call j covers dk rows j*16 + (l>>2)
  const bf16_t* Vg = VT + ((size_t)bh * 64 + (l >> 2)) * Sn + w * 32 + (l & 3) * 8;

  f32x4 lacca = f32x4{0.f, 0.f, 0.f, 0.f};
  f32x4 laccb = f32x4{0.f, 0.f, 0.f, 0.f};
  f32x4 oacca[4], oaccb[4];
#pragma unroll
  for (int md = 0; md < 4; ++md) {
    oacca[md] = f32x4{0.f, 0.f, 0.f, 0.f};
    oaccb[md] = f32x4{0.f, 0.f, 0.f, 0.f};
  }

  auto stage = [&](int kv0, int buf) {
#pragma unroll
    for (int rb = 0; rb < 2; ++rb)
#pragma unroll
      for (int hh = 0; hh < 2; ++hh)
        gl_lds16(Kg + (size_t)(kv0 + rb * 64) * Dn + hh * 32,
                 (char*)&Ks[buf][0] + hh * 8192 + rb * 4096 + w * 1024);
#pragma unroll
    for (int j = 0; j < 4; ++j)
      gl_lds16(Vg + kv0 + (size_t)j * 16 * Sn,
               (char*)&Vs[buf][0] + w * 4096 + j * 1024);
  };

  stage(0, 0);
  for (int it = 0; it < Sn / 128; ++it) {
    __syncthreads();
    if (it + 1 < Sn / 128) stage((it + 1) * 128, (it + 1) & 1);
    const bf16_t* Kb = &Ks[it & 1][0];
    const bf16_t* Vb = &Vs[it & 1][0];

    // S^T: 8 tiles of (16 kv x 16 q) per q-subtile; K frags read once, used twice
    f32x4 sa[8], sb[8];
#pragma unroll
    for (int ns = 0; ns < 8; ++ns) {
      const bf16x8 k0 = *(const bf16x8*)&Kb[(ns * 16 + mloc) * 32 + kblk * 8];
      const bf16x8 k1 = *(const bf16x8*)&Kb[4096 + (ns * 16 + mloc) * 32 + kblk * 8];
      f32x4 a = f32x4{0.f, 0.f, 0.f, 0.f};
      a = MFMA_B16(k0, qfa0, a);
      a = MFMA_B16(k1, qfa1, a);
      sa[ns] = a;
      f32x4 c = f32x4{0.f, 0.f, 0.f, 0.f};
      c = MFMA_B16(k0, qfb0, c);
      c = MFMA_B16(k1, qfb1, c);
      sb[ns] = c;
    }

    // P = exp2(S^T); P^T B-fragments from own registers (σ alignment)
    bf16x8 pa[4], pbv[4];
#pragma unroll
    for (int ns = 0; ns < 8; ++ns)
#pragma unroll
      for (int r = 0; r < 4; ++r) {
        pa[ns >> 1][(ns & 1) * 4 + r]  = (bf16_t)__builtin_amdgcn_exp2f(sa[ns][r]);
        pbv[ns >> 1][(ns & 1) * 4 + r] = (bf16_t)__builtin_amdgcn_exp2f(sb[ns][r]);
      }

#pragma unroll
    for (int c = 0; c < 4; ++c) {
      lacca = MFMA_B16(ones, pa[c], lacca);
      laccb = MFMA_B16(ones, pbv[c], laccb);
    }

    // O^T += V^T · P^T; V frags read once, used twice
#pragma unroll
    for (int md = 0; md < 4; ++md)
#pragma unroll
      for (int c = 0; c < 4; ++c) {
        const bf16x8 v = *(const bf16x8*)&Vb[c * 2048 + (md * 16 + mloc) * 32 + kblk * 8];
        oacca[md] = MFMA_B16(v, pa[c], oacca[md]);
        oaccb[md] = MFMA_B16(v, pbv[c], oaccb[md]);
      }
  }

  const float invA = 1.0f / lacca[0];
  const float invB = 1.0f / laccb[0];
  const size_t obA = (size_t)(b * Sn + q0 + w * 32 + mloc) * Dn + h * 64 + kblk * 4;
  const size_t obB = obA + (size_t)16 * Dn;
#pragma unroll
  for (int md = 0; md < 4; ++md) {
    bf16x4 oa, ob;
#pragma unroll
    for (int r = 0; r < 4; ++r) {
      oa[r] = (bf16_t)(oacca[md][r] * invA);
      ob[r] = (bf16_t)(oaccb[md][r] * invB);
    }
    *(bf16x4*)&O[obA + md * 16] = oa;
    *(bf16x4*)&O[obB + md * 16] = ob;
  }
}

// ---------------- host launch ----------------
extern "C" void kernel_launch(void* const* d_in, const int* in_sizes, int n_in,
                              void* d_out, int out_size, void* d_ws, size_t ws_size,
                              hipStream_t stream) {
  (void)in_sizes; (void)n_in; (void)out_size; (void)ws_size;
  const float* x    = (const float*)d_in[0];
  const float* wq_w = (const float*)d_in[1];
  const float* wq_b = (const float*)d_in[2];
  const float* wk_w = (const float*)d_in[3];
  const float* wk_b = (const float*)d_in[4];
  const float* wv_w = (const float*)d_in[5];
  const float* wv_b = (const float*)d_in[6];
  const float* wo_w = (const float*)d_in[7];
  const float* wo_b = (const float*)d_in[8];
  const float* ln_g = (const float*)d_in[9];
  const float* ln_b = (const float*)d_in[10];
  const float* w1   = (const float*)d_in[11];
  const float* b1   = (const float*)d_in[12];
  const float* w2   = (const float*)d_in[13];
  const float* b2   = (const float*)d_in[14];

  char* ws = (char*)d_ws;
  size_t o = 0;
  bf16_t* WqkvT = (bf16_t*)(ws + o); o += (size_t)2304 * 768 * 2;
  bf16_t* WoT   = (bf16_t*)(ws + o); o += (size_t)768 * 768 * 2;
  bf16_t* W1T   = (bf16_t*)(ws + o); o += (size_t)3072 * 768 * 2;
  bf16_t* W2T   = (bf16_t*)(ws + o); o += (size_t)768 * 3072 * 2;
  float*  QKVB  = (float*)(ws + o);  o += (size_t)2304 * 4;
  bf16_t* Hbuf  = (bf16_t*)(ws + o); o += (size_t)NTOK * 768 * 2;  // h, later reused as o
  bf16_t* Qb    = (bf16_t*)(ws + o); o += (size_t)NTOK * 768 * 2;
  bf16_t* Kb    = (bf16_t*)(ws + o); o += (size_t)NTOK * 768 * 2;
  bf16_t* VbT   = (bf16_t*)(ws + o); o += (size_t)NTOK * 768 * 2;  // [b*12+h][64][2048]
  float*  Ybuf  = (float*)(ws + o);  o += (size_t)NTOK * 768 * 4;
  bf16_t* Zbuf  = (bf16_t*)(ws + o); o += (size_t)NTOK * 768 * 2;
  bf16_t* Ubuf  = (bf16_t*)(ws + o); o += (size_t)NTOK * 3072 * 2;

  // --- weight prep + LN1 fused ---
  k_prep<<<1729 + NTOK, 256, 0, stream>>>(wq_w, wk_w, wv_w, wo_w, w1, w2,
                                          wq_b, wk_b, wv_b, WqkvT, WoT, W1T, W2T, QKVB,
                                          x, ln_g, ln_b, Hbuf);

  // --- Q,K projection (Q pre-scaled): 128x64 BK=64, 768 blocks single pass ---
  k_gemm<128, 64, 64, EPI_QK, 3, 1><<<dim3(24, 32), 256, 0, stream>>>(Hbuf, WqkvT, 1536, 768,
                                                                      QKVB, nullptr, Qb, Kb);

  // --- V^T projection: A = Wv^T [768 x 768], B = Hbuf -> VbT coalesced ---
  k_gemm<64, 64, 64, EPI_VT, 4, 0><<<dim3(64, 12), 256, 0, stream>>>(WqkvT + (size_t)2 * 589824, Hbuf,
                                                                     4096, 768, QKVB + 1536, nullptr,
                                                                     VbT, nullptr);

  // --- attention -> o (reuses Hbuf): 384 blocks, single pass, 2 q-subtiles/wave ---
  k_attn<<<dim3(Sn / 128, Bn * Hn), 256, 0, stream>>>(Qb, Kb, VbT, Hbuf);

  // --- y = o @ Wo + wo_b + x ---
  k_gemm<64, 64, 64, EPI_Y, 4, 1><<<dim3(12, 64), 256, 0, stream>>>(Hbuf, WoT, 768, 768,
                                                                    wo_b, x, Ybuf, nullptr);

  // --- LN2 -> z ---
  k_layernorm<<<NTOK, 256, 0, stream>>>(Ybuf, ln_g, ln_b, Zbuf);

  // --- FFN1 + exact GELU -> u: BK=64, 12 rounds ---
  k_gemm<128, 128, 64, EPI_GELU, 2, 1><<<dim3(24, 32), 256, 0, stream>>>(Zbuf, W1T, 3072, 768,
                                                                         b1, nullptr, Ubuf, nullptr);

  // --- FFN2 + b2 + y -> out: BK=128, 24 rounds ---
  k_gemm<64, 64, 128, EPI_OUT, 2, 1><<<dim3(12, 64), 256, 0, stream>>>(Ubuf, W2T, 768, 3072,
                                                                       b2, Ybuf, d_out, nullptr);
}

// Round 12
// 267.910 us; speedup vs baseline: 1.0850x; 1.0850x over previous
//
#include <hip/hip_runtime.h>
#include <hip/hip_bf16.h>
#include <math.h>

typedef __bf16 bf16_t;
typedef __bf16 bf16x8 __attribute__((ext_vector_type(8)));
typedef __bf16 bf16x4 __attribute__((ext_vector_type(4)));
typedef float f32x4 __attribute__((ext_vector_type(4)));

#define MFMA_B16(a, b, c) __builtin_amdgcn_mfma_f32_16x16x32_bf16((a), (b), (c), 0, 0, 0)

static constexpr int Bn = 2, Sn = 2048, Dn = 768, Hn = 12, Fn = 3072;
static constexpr int NTOK = Bn * Sn;  // 4096
// 0.125 (1/sqrt(dk)) * log2(e): folded into Q so softmax uses exp2
#define QSCALE 0.18033688011112042f

// async global->LDS, 16B per lane; lds base wave-uniform (HW adds lane*16).
// R4-R8 evidence: gl_lds16 staging never spills; manual VGPR staging always does.
__device__ __forceinline__ void gl_lds16(const bf16_t* g, void* lds) {
  __builtin_amdgcn_global_load_lds(
      (const __attribute__((address_space(1))) uint32_t*)g,
      (__attribute__((address_space(3))) uint32_t*)lds, 16, 0, 0);
}

// ---------------- prep: weight transposes + bias concat + LN1, one dispatch ----------------
__global__ __launch_bounds__(256) void k_prep(const float* __restrict__ wq, const float* __restrict__ wk,
                                              const float* __restrict__ wv, const float* __restrict__ wo,
                                              const float* __restrict__ w1, const float* __restrict__ w2,
                                              const float* __restrict__ bq, const float* __restrict__ bk,
                                              const float* __restrict__ bv,
                                              bf16_t* __restrict__ WqkvT, bf16_t* __restrict__ WoT,
                                              bf16_t* __restrict__ W1T, bf16_t* __restrict__ W2T,
                                              float* __restrict__ QKVB,
                                              const float* __restrict__ x, const float* __restrict__ ln_g,
                                              const float* __restrict__ ln_b, bf16_t* __restrict__ Hbuf) {
  int t = blockIdx.x;
  int tid = threadIdx.x;
  if (t >= 1729) {  // --- LayerNorm branch ---
    int tok = t - 1729;
    const float* xr = x + (size_t)tok * Dn;
    float v0 = xr[tid], v1 = xr[tid + 256], v2 = xr[tid + 512];
    float s = v0 + v1 + v2;
    float ss = v0 * v0 + v1 * v1 + v2 * v2;
    __shared__ float red[8];
#pragma unroll
    for (int off = 32; off > 0; off >>= 1) {
      s += __shfl_down(s, off);
      ss += __shfl_down(ss, off);
    }
    int w = tid >> 6, l = tid & 63;
    if (l == 0) { red[w] = s; red[4 + w] = ss; }
    __syncthreads();
    s = red[0] + red[1] + red[2] + red[3];
    ss = red[4] + red[5] + red[6] + red[7];
    float mu = s * (1.0f / Dn);
    float var = ss * (1.0f / Dn) - mu * mu;
    float rstd = rsqrtf(var + 1e-5f);
    bf16_t* orow = Hbuf + (size_t)tok * Dn;
    orow[tid]       = (bf16_t)((v0 - mu) * rstd * ln_g[tid]       + ln_b[tid]);
    orow[tid + 256] = (bf16_t)((v1 - mu) * rstd * ln_g[tid + 256] + ln_b[tid + 256]);
    orow[tid + 512] = (bf16_t)((v2 - mu) * rstd * ln_g[tid + 512] + ln_b[tid + 512]);
    return;
  }
  if (t == 1728) {
    for (int i = tid; i < 2304; i += 256)
      QKVB[i] = i < 768 ? bq[i] : (i < 1536 ? bk[i - 768] : bv[i - 1536]);
    return;
  }
  __shared__ float T[64][65];
  const float* src;
  bf16_t* dst;
  int P, Q, tp, tq;
  if (t < 432) {
    int pb = t / 12; tp = t - pb * 12; tq = 0;
    int proj = pb / 12, head = pb - proj * 12;
    src = (proj == 0 ? wq : proj == 1 ? wk : wv) + (size_t)head * 768 * 64;
    dst = WqkvT + (size_t)proj * 589824 + (size_t)head * 64 * 768;
    P = 768; Q = 64;
  } else if (t < 576) {
    int u = t - 432; tp = u / 12; tq = u - tp * 12;
    src = wo; dst = WoT; P = 768; Q = 768;
  } else if (t < 1152) {
    int u = t - 576; tp = u / 48; tq = u - tp * 48;
    src = w1; dst = W1T; P = 768; Q = 3072;
  } else {
    int u = t - 1152; tp = u / 12; tq = u - tp * 12;
    src = w2; dst = W2T; P = 3072; Q = 768;
  }
  int j = tid & 63, i0 = tid >> 6;
#pragma unroll
  for (int i = i0; i < 64; i += 4)
    T[i][j] = src[(size_t)(tp * 64 + i) * Q + tq * 64 + j];
  __syncthreads();
#pragma unroll
  for (int i = i0; i < 64; i += 4)
    dst[(size_t)(tq * 64 + i) * P + tp * 64 + j] = (bf16_t)T[j][i];
}

// ---------------- LayerNorm over D=768, one token per block (LN2) ----------------
__global__ __launch_bounds__(256) void k_layernorm(const float* __restrict__ x,
                                                   const float* __restrict__ g,
                                                   const float* __restrict__ bb,
                                                   bf16_t* __restrict__ out) {
  int t = blockIdx.x, tid = threadIdx.x;
  const float* xr = x + (size_t)t * Dn;
  float v0 = xr[tid], v1 = xr[tid + 256], v2 = xr[tid + 512];
  float s = v0 + v1 + v2;
  float ss = v0 * v0 + v1 * v1 + v2 * v2;
  __shared__ float red[8];
#pragma unroll
  for (int off = 32; off > 0; off >>= 1) {
    s += __shfl_down(s, off);
    ss += __shfl_down(ss, off);
  }
  int w = tid >> 6, l = tid & 63;
  if (l == 0) { red[w] = s; red[4 + w] = ss; }
  __syncthreads();
  s = red[0] + red[1] + red[2] + red[3];
  ss = red[4] + red[5] + red[6] + red[7];
  float mu = s * (1.0f / Dn);
  float var = ss * (1.0f / Dn) - mu * mu;
  float rstd = rsqrtf(var + 1e-5f);
  bf16_t* orow = out + (size_t)t * Dn;
  orow[tid]       = (bf16_t)((v0 - mu) * rstd * g[tid]       + bb[tid]);
  orow[tid + 256] = (bf16_t)((v1 - mu) * rstd * g[tid + 256] + bb[tid + 256]);
  orow[tid + 512] = (bf16_t)((v2 - mu) * rstd * g[tid + 512] + bb[tid + 512]);
}

// ---------------- bf16 MFMA GEMM, gl_lds16 staging, BK in {32,64} as stacked halves ----------------
// R11 lesson: BK=128 (and any config with >1 resident pass) regresses — keep BK<=64,
// single pass (grid <= OCC*256), OCC>=3 where LDS permits.
enum { EPI_QK = 0, EPI_VT = 1, EPI_Y = 2, EPI_GELU = 3, EPI_OUT = 4 };

template <int MT, int NT, int BK, int EPI, int OCC, int SWZ>
__global__ __launch_bounds__(256, OCC) void k_gemm(const bf16_t* __restrict__ A,
                                                   const bf16_t* __restrict__ Bt,
                                                   int N, int K,
                                                   const float* __restrict__ bias,
                                                   const float* __restrict__ resid,
                                                   void* __restrict__ out0,
                                                   void* __restrict__ out1) {
  constexpr int MI = MT / 32, NI = NT / 32;
  constexpr int WROWS = MT / 2, WCOLS = NT / 2;
  constexpr int KS = BK / 32;                 // MFMA k-steps (= LDS halves) per round
  __shared__ __align__(16) bf16_t As[2][MT * BK];
  __shared__ __align__(16) bf16_t Bs[2][NT * BK];
  const int tid = threadIdx.x;
  const int w = tid >> 6, l = tid & 63;
  const int wm = w >> 1, wn = w & 1;
  const int mloc = l & 15, kblk = l >> 4;
  int bx = blockIdx.x, by = blockIdx.y;
  if constexpr (SWZ) {  // requires gridDim.y % 8 == 0
    int lin = by * gridDim.x + bx;
    int xcd = lin & 7, s = lin >> 3;
    by = xcd * (gridDim.y >> 3) + s / gridDim.x;
    bx = s - (s / gridDim.x) * gridDim.x;
  }

  f32x4 acc[MI][NI];
#pragma unroll
  for (int i = 0; i < MI; ++i)
#pragma unroll
    for (int j = 0; j < NI; ++j) acc[i][j] = f32x4{0.f, 0.f, 0.f, 0.f};

  const bf16_t* gA = A + (size_t)(by * MT + (tid >> 2)) * K + (tid & 3) * 8;
  const bf16_t* gB = Bt + (size_t)(bx * NT + (tid >> 2)) * K + (tid & 3) * 8;
  const int nk = K / BK;

  auto stage = [&](int kt, int buf) {
#pragma unroll
    for (int h = 0; h < KS; ++h) {
#pragma unroll
      for (int rb = 0; rb < MT / 64; ++rb)
        gl_lds16(gA + (size_t)rb * 64 * K + kt * BK + h * 32,
                 (char*)&As[buf][0] + h * (MT * 64) + rb * 4096 + w * 1024);
#pragma unroll
      for (int rb = 0; rb < NT / 64; ++rb)
        gl_lds16(gB + (size_t)rb * 64 * K + kt * BK + h * 32,
                 (char*)&Bs[buf][0] + h * (NT * 64) + rb * 4096 + w * 1024);
    }
  };

  stage(0, 0);
  for (int kt = 0; kt < nk; ++kt) {
    __syncthreads();
    if (kt + 1 < nk) stage(kt + 1, (kt + 1) & 1);
    const bf16_t* Ab = &As[kt & 1][0];
    const bf16_t* Bb = &Bs[kt & 1][0];
    bf16x8 af[MI][KS], bfv[NI][KS];
#pragma unroll
    for (int mi = 0; mi < MI; ++mi)
#pragma unroll
      for (int ks = 0; ks < KS; ++ks)
        af[mi][ks] = *(const bf16x8*)&Ab[ks * (MT * 32) + (wm * WROWS + mi * 16 + mloc) * 32 + kblk * 8];
#pragma unroll
    for (int ni = 0; ni < NI; ++ni)
#pragma unroll
      for (int ks = 0; ks < KS; ++ks)
        bfv[ni][ks] = *(const bf16x8*)&Bb[ks * (NT * 32) + (wn * WCOLS + ni * 16 + mloc) * 32 + kblk * 8];
#pragma unroll
    for (int ks = 0; ks < KS; ++ks)
#pragma unroll
      for (int mi = 0; mi < MI; ++mi)
#pragma unroll
        for (int ni = 0; ni < NI; ++ni)
          acc[mi][ni] = MFMA_B16(af[mi][ks], bfv[ni][ks], acc[mi][ni]);
  }

  const int gmb = by * MT + wm * WROWS + kblk * 4;
  const int gnb = bx * NT + wn * WCOLS + mloc;
  if constexpr (EPI == EPI_QK) {
    constexpr int TPP = 768 / NT;  // n-tiles per projection
    const int proj = bx / TPP;     // 0 = Q (scaled), 1 = K
#pragma unroll
    for (int mi = 0; mi < MI; ++mi)
#pragma unroll
      for (int ni = 0; ni < NI; ++ni) {
        int gn = gnb + ni * 16;
        float bv = bias[gn];
        int gm0 = gmb + mi * 16;
        if (proj == 0) {
          bf16_t* dst = (bf16_t*)out0;
#pragma unroll
          for (int r = 0; r < 4; ++r)
            dst[(size_t)(gm0 + r) * 768 + gn] = (bf16_t)((acc[mi][ni][r] + bv) * QSCALE);
        } else {
          bf16_t* dst = (bf16_t*)out1;
#pragma unroll
          for (int r = 0; r < 4; ++r)
            dst[(size_t)(gm0 + r) * 768 + (gn - 768)] = (bf16_t)(acc[mi][ni][r] + bv);
        }
      }
  } else if constexpr (EPI == EPI_VT) {
    bf16_t* dst = (bf16_t*)out0;
#pragma unroll
    for (int mi = 0; mi < MI; ++mi)
#pragma unroll
      for (int ni = 0; ni < NI; ++ni) {
        int gn = gnb + ni * 16;
        int bq = gn >> 11, sq = gn & 2047;
#pragma unroll
        for (int r = 0; r < 4; ++r) {
          int gm = gmb + mi * 16 + r;
          int hq = gm >> 6, dk = gm & 63;
          dst[((size_t)(bq * Hn + hq) * 64 + dk) * Sn + sq] = (bf16_t)(acc[mi][ni][r] + bias[gm]);
        }
      }
  } else if constexpr (EPI == EPI_GELU) {
    bf16_t* dst = (bf16_t*)out0;
#pragma unroll
    for (int mi = 0; mi < MI; ++mi)
#pragma unroll
      for (int ni = 0; ni < NI; ++ni) {
        int gn = gnb + ni * 16;
        float bv = bias[gn];
#pragma unroll
        for (int r = 0; r < 4; ++r) {
          int gm = gmb + mi * 16 + r;
          float t = acc[mi][ni][r] + bv;
          float ge = 0.5f * t * (1.0f + erff(t * 0.70710678118654752f));
          dst[(size_t)gm * N + gn] = (bf16_t)ge;
        }
      }
  } else {  // EPI_Y / EPI_OUT: + bias + residual, fp32 out
    float* dst = (float*)out0;
#pragma unroll
    for (int mi = 0; mi < MI; ++mi)
#pragma unroll
      for (int ni = 0; ni < NI; ++ni) {
        int gn = gnb + ni * 16;
        float bv = bias[gn];
#pragma unroll
        for (int r = 0; r < 4; ++r) {
          int gm = gmb + mi * 16 + r;
          dst[(size_t)gm * N + gn] = acc[mi][ni][r] + bv + resid[(size_t)gm * N + gn];
        }
      }
  }
}

// ---------------- flash attention: 256 threads, 128 q-rows/block, 2 q-subtiles per wave ----------------
// Each wave computes 32 q-columns (two B-fragments) so every K/V LDS fragment read
// feeds 2 MFMAs — halves per-CU LDS read traffic. Grid (16,24)=384 blocks, LDS 64 KB,
// OCC=2: single pass. Fixed-max softmax (scores bounded, exp2 safe); σ-permuted K rows
// keep the PV B-operand (P^T) in each lane's own registers; V consumed as V^T.
__global__ __launch_bounds__(256, 2) void k_attn(const bf16_t* __restrict__ Q,
                                                 const bf16_t* __restrict__ K,
                                                 const bf16_t* __restrict__ VT,
                                                 bf16_t* __restrict__ O) {
  __shared__ __align__(16) bf16_t Ks[2][8192];  // [buf][dk-half(4096 el)][128 rows σ][32]
  __shared__ __align__(16) bf16_t Vs[2][8192];  // [buf][kv-chunk(2048 el)][64 dk][32]
  const int tid = threadIdx.x, w = tid >> 6, l = tid & 63;
  const int mloc = l & 15, kblk = l >> 4;
  const int bh = blockIdx.y, b = bh / Hn, h = bh - b * Hn;
  const int q0 = blockIdx.x * 128;

  // two q-subtiles per wave: qa = q0 + w*32 + mloc, qb = qa + 16
  const size_t qoffA = (size_t)(b * Sn + q0 + w * 32 + mloc) * Dn + h * 64 + kblk * 8;
  const bf16x8 qfa0 = *(const bf16x8*)(Q + qoffA);
  const bf16x8 qfa1 = *(const bf16x8*)(Q + qoffA + 32);
  const bf16x8 qfb0 = *(const bf16x8*)(Q + qoffA + (size_t)16 * Dn);
  const bf16x8 qfb1 = *(const bf16x8*)(Q + qoffA + (size_t)16 * Dn + 32);

  bf16x8 ones;
#pragma unroll
  for (int j = 0; j < 8; ++j) ones[j] = (bf16_t)1.0f;

  // K staging: thread covers σ-row of tq in [0,64); rb adds +64 (σ passes bit 6 through)
  const int tq = tid >> 2, q4 = tid & 3;
  const int s0 = (tq & 0x20) | ((tq & 0x0C) << 1) | ((tq & 0x10) >> 2) | (tq & 3);
  const bf16_t* Kg = K + (size_t)(b * Sn + s0) * Dn + h * 64 + q4 * 8;
  // V staging: wave w owns kv-chunk w; call j covers dk rows j*16 + (l>>2)
  const bf16_t* Vg = VT + ((size_t)bh * 64 + (l >> 2)) * Sn + w * 32 + (l & 3) * 8;

  f32x4 lacca = f32x4{0.f, 0.f, 0.f, 0.f};
  f32x4 laccb = f32x4{0.f, 0.f, 0.f, 0.f};
  f32x4 oacca[4], oaccb[4];
#pragma unroll
  for (int md = 0; md < 4; ++md) {
    oacca[md] = f32x4{0.f, 0.f, 0.f, 0.f};
    oaccb[md] = f32x4{0.f, 0.f, 0.f, 0.f};
  }

  auto stage = [&](int kv0, int buf) {
#pragma unroll
    for (int rb = 0; rb < 2; ++rb)
#pragma unroll
      for (int hh = 0; hh < 2; ++hh)
        gl_lds16(Kg + (size_t)(kv0 + rb * 64) * Dn + hh * 32,
                 (char*)&Ks[buf][0] + hh * 8192 + rb * 4096 + w * 1024);
#pragma unroll
    for (int j = 0; j < 4; ++j)
      gl_lds16(Vg + kv0 + (size_t)j * 16 * Sn,
               (char*)&Vs[buf][0] + w * 4096 + j * 1024);
  };

  stage(0, 0);
  for (int it = 0; it < Sn / 128; ++it) {
    __syncthreads();
    if (it + 1 < Sn / 128) stage((it + 1) * 128, (it + 1) & 1);
    const bf16_t* Kb = &Ks[it & 1][0];
    const bf16_t* Vb = &Vs[it & 1][0];

    // S^T: 8 tiles of (16 kv x 16 q) per q-subtile; K frags read once, used twice
    f32x4 sa[8], sb[8];
#pragma unroll
    for (int ns = 0; ns < 8; ++ns) {
      const bf16x8 k0 = *(const bf16x8*)&Kb[(ns * 16 + mloc) * 32 + kblk * 8];
      const bf16x8 k1 = *(const bf16x8*)&Kb[4096 + (ns * 16 + mloc) * 32 + kblk * 8];
      f32x4 a = f32x4{0.f, 0.f, 0.f, 0.f};
      a = MFMA_B16(k0, qfa0, a);
      a = MFMA_B16(k1, qfa1, a);
      sa[ns] = a;
      f32x4 c = f32x4{0.f, 0.f, 0.f, 0.f};
      c = MFMA_B16(k0, qfb0, c);
      c = MFMA_B16(k1, qfb1, c);
      sb[ns] = c;
    }

    // P = exp2(S^T); P^T B-fragments from own registers (σ alignment)
    bf16x8 pa[4], pbv[4];
#pragma unroll
    for (int ns = 0; ns < 8; ++ns)
#pragma unroll
      for (int r = 0; r < 4; ++r) {
        pa[ns >> 1][(ns & 1) * 4 + r]  = (bf16_t)__builtin_amdgcn_exp2f(sa[ns][r]);
        pbv[ns >> 1][(ns & 1) * 4 + r] = (bf16_t)__builtin_amdgcn_exp2f(sb[ns][r]);
      }

#pragma unroll
    for (int c = 0; c < 4; ++c) {
      lacca = MFMA_B16(ones, pa[c], lacca);
      laccb = MFMA_B16(ones, pbv[c], laccb);
    }

    // O^T += V^T · P^T; V frags read once, used twice
#pragma unroll
    for (int md = 0; md < 4; ++md)
#pragma unroll
      for (int c = 0; c < 4; ++c) {
        const bf16x8 v = *(const bf16x8*)&Vb[c * 2048 + (md * 16 + mloc) * 32 + kblk * 8];
        oacca[md] = MFMA_B16(v, pa[c], oacca[md]);
        oaccb[md] = MFMA_B16(v, pbv[c], oaccb[md]);
      }
  }

  const float invA = 1.0f / lacca[0];
  const float invB = 1.0f / laccb[0];
  const size_t obA = (size_t)(b * Sn + q0 + w * 32 + mloc) * Dn + h * 64 + kblk * 4;
  const size_t obB = obA + (size_t)16 * Dn;
#pragma unroll
  for (int md = 0; md < 4; ++md) {
    bf16x4 oa, ob;
#pragma unroll
    for (int r = 0; r < 4; ++r) {
      oa[r] = (bf16_t)(oacca[md][r] * invA);
      ob[r] = (bf16_t)(oaccb[md][r] * invB);
    }
    *(bf16x4*)&O[obA + md * 16] = oa;
    *(bf16x4*)&O[obB + md * 16] = ob;
  }
}

// ---------------- host launch ----------------
extern "C" void kernel_launch(void* const* d_in, const int* in_sizes, int n_in,
                              void* d_out, int out_size, void* d_ws, size_t ws_size,
                              hipStream_t stream) {
  (void)in_sizes; (void)n_in; (void)out_size; (void)ws_size;
  const float* x    = (const float*)d_in[0];
  const float* wq_w = (const float*)d_in[1];
  const float* wq_b = (const float*)d_in[2];
  const float* wk_w = (const float*)d_in[3];
  const float* wk_b = (const float*)d_in[4];
  const float* wv_w = (const float*)d_in[5];
  const float* wv_b = (const float*)d_in[6];
  const float* wo_w = (const float*)d_in[7];
  const float* wo_b = (const float*)d_in[8];
  const float* ln_g = (const float*)d_in[9];
  const float* ln_b = (const float*)d_in[10];
  const float* w1   = (const float*)d_in[11];
  const float* b1   = (const float*)d_in[12];
  const float* w2   = (const float*)d_in[13];
  const float* b2   = (const float*)d_in[14];

  char* ws = (char*)d_ws;
  size_t o = 0;
  bf16_t* WqkvT = (bf16_t*)(ws + o); o += (size_t)2304 * 768 * 2;
  bf16_t* WoT   = (bf16_t*)(ws + o); o += (size_t)768 * 768 * 2;
  bf16_t* W1T   = (bf16_t*)(ws + o); o += (size_t)3072 * 768 * 2;
  bf16_t* W2T   = (bf16_t*)(ws + o); o += (size_t)768 * 3072 * 2;
  float*  QKVB  = (float*)(ws + o);  o += (size_t)2304 * 4;
  bf16_t* Hbuf  = (bf16_t*)(ws + o); o += (size_t)NTOK * 768 * 2;  // h, later reused as o
  bf16_t* Qb    = (bf16_t*)(ws + o); o += (size_t)NTOK * 768 * 2;
  bf16_t* Kb    = (bf16_t*)(ws + o); o += (size_t)NTOK * 768 * 2;
  bf16_t* VbT   = (bf16_t*)(ws + o); o += (size_t)NTOK * 768 * 2;  // [b*12+h][64][2048]
  float*  Ybuf  = (float*)(ws + o);  o += (size_t)NTOK * 768 * 4;
  bf16_t* Zbuf  = (bf16_t*)(ws + o); o += (size_t)NTOK * 768 * 2;
  bf16_t* Ubuf  = (bf16_t*)(ws + o); o += (size_t)NTOK * 3072 * 2;

  // --- weight prep + LN1 fused ---
  k_prep<<<1729 + NTOK, 256, 0, stream>>>(wq_w, wk_w, wv_w, wo_w, w1, w2,
                                          wq_b, wk_b, wv_b, WqkvT, WoT, W1T, W2T, QKVB,
                                          x, ln_g, ln_b, Hbuf);

  // --- Q,K projection (Q pre-scaled): 128x64 BK=64, 768 blocks single pass ---
  k_gemm<128, 64, 64, EPI_QK, 3, 1><<<dim3(24, 32), 256, 0, stream>>>(Hbuf, WqkvT, 1536, 768,
                                                                      QKVB, nullptr, Qb, Kb);

  // --- V^T projection: A = Wv^T [768 x 768], B = Hbuf -> VbT coalesced ---
  k_gemm<64, 64, 64, EPI_VT, 4, 0><<<dim3(64, 12), 256, 0, stream>>>(WqkvT + (size_t)2 * 589824, Hbuf,
                                                                     4096, 768, QKVB + 1536, nullptr,
                                                                     VbT, nullptr);

  // --- attention -> o (reuses Hbuf): 384 blocks, single pass, 2 q-subtiles/wave ---
  k_attn<<<dim3(Sn / 128, Bn * Hn), 256, 0, stream>>>(Qb, Kb, VbT, Hbuf);

  // --- y = o @ Wo + wo_b + x ---
  k_gemm<64, 64, 64, EPI_Y, 4, 1><<<dim3(12, 64), 256, 0, stream>>>(Hbuf, WoT, 768, 768,
                                                                    wo_b, x, Ybuf, nullptr);

  // --- LN2 -> z ---
  k_layernorm<<<NTOK, 256, 0, stream>>>(Ybuf, ln_g, ln_b, Zbuf);

  // --- FFN1 + exact GELU -> u: R10 known-good config ---
  k_gemm<128, 128, 32, EPI_GELU, 3, 1><<<dim3(24, 32), 256, 0, stream>>>(Zbuf, W1T, 3072, 768,
                                                                         b1, nullptr, Ubuf, nullptr);

  // --- FFN2 + b2 + y -> out: R10 known-good config (BK=64, 48 rounds, single pass) ---
  k_gemm<64, 64, 64, EPI_OUT, 4, 1><<<dim3(12, 64), 256, 0, stream>>>(Ubuf, W2T, 768, 3072,
                                                                      b2, Ybuf, d_out, nullptr);
}

// Round 13
// 265.610 us; speedup vs baseline: 1.0944x; 1.0087x over previous
//
#include <hip/hip_runtime.h>
#include <hip/hip_bf16.h>
#include <math.h>

typedef __bf16 bf16_t;
typedef __bf16 bf16x8 __attribute__((ext_vector_type(8)));
typedef __bf16 bf16x4 __attribute__((ext_vector_type(4)));
typedef float f32x4 __attribute__((ext_vector_type(4)));

#define MFMA_B16(a, b, c) __builtin_amdgcn_mfma_f32_16x16x32_bf16((a), (b), (c), 0, 0, 0)

static constexpr int Bn = 2, Sn = 2048, Dn = 768, Hn = 12, Fn = 3072;
static constexpr int NTOK = Bn * Sn;  // 4096
// 0.125 (1/sqrt(dk)) * log2(e): folded into Q so softmax uses exp2
#define QSCALE 0.18033688011112042f

// async global->LDS, 16B per lane; lds base wave-uniform (HW adds lane*16).
// R4-R8 evidence: gl_lds16 staging never spills; manual VGPR staging always does.
__device__ __forceinline__ void gl_lds16(const bf16_t* g, void* lds) {
  __builtin_amdgcn_global_load_lds(
      (const __attribute__((address_space(1))) uint32_t*)g,
      (__attribute__((address_space(3))) uint32_t*)lds, 16, 0, 0);
}

// ---------------- prep: weight transposes + bias concat + LN1, one dispatch ----------------
__global__ __launch_bounds__(256) void k_prep(const float* __restrict__ wq, const float* __restrict__ wk,
                                              const float* __restrict__ wv, const float* __restrict__ wo,
                                              const float* __restrict__ w1, const float* __restrict__ w2,
                                              const float* __restrict__ bq, const float* __restrict__ bk,
                                              const float* __restrict__ bv,
                                              bf16_t* __restrict__ WqkvT, bf16_t* __restrict__ WoT,
                                              bf16_t* __restrict__ W1T, bf16_t* __restrict__ W2T,
                                              float* __restrict__ QKVB,
                                              const float* __restrict__ x, const float* __restrict__ ln_g,
                                              const float* __restrict__ ln_b, bf16_t* __restrict__ Hbuf) {
  int t = blockIdx.x;
  int tid = threadIdx.x;
  if (t >= 1729) {  // --- LayerNorm branch ---
    int tok = t - 1729;
    const float* xr = x + (size_t)tok * Dn;
    float v0 = xr[tid], v1 = xr[tid + 256], v2 = xr[tid + 512];
    float s = v0 + v1 + v2;
    float ss = v0 * v0 + v1 * v1 + v2 * v2;
    __shared__ float red[8];
#pragma unroll
    for (int off = 32; off > 0; off >>= 1) {
      s += __shfl_down(s, off);
      ss += __shfl_down(ss, off);
    }
    int w = tid >> 6, l = tid & 63;
    if (l == 0) { red[w] = s; red[4 + w] = ss; }
    __syncthreads();
    s = red[0] + red[1] + red[2] + red[3];
    ss = red[4] + red[5] + red[6] + red[7];
    float mu = s * (1.0f / Dn);
    float var = ss * (1.0f / Dn) - mu * mu;
    float rstd = rsqrtf(var + 1e-5f);
    bf16_t* orow = Hbuf + (size_t)tok * Dn;
    orow[tid]       = (bf16_t)((v0 - mu) * rstd * ln_g[tid]       + ln_b[tid]);
    orow[tid + 256] = (bf16_t)((v1 - mu) * rstd * ln_g[tid + 256] + ln_b[tid + 256]);
    orow[tid + 512] = (bf16_t)((v2 - mu) * rstd * ln_g[tid + 512] + ln_b[tid + 512]);
    return;
  }
  if (t == 1728) {
    for (int i = tid; i < 2304; i += 256)
      QKVB[i] = i < 768 ? bq[i] : (i < 1536 ? bk[i - 768] : bv[i - 1536]);
    return;
  }
  __shared__ float T[64][65];
  const float* src;
  bf16_t* dst;
  int P, Q, tp, tq;
  if (t < 432) {
    int pb = t / 12; tp = t - pb * 12; tq = 0;
    int proj = pb / 12, head = pb - proj * 12;
    src = (proj == 0 ? wq : proj == 1 ? wk : wv) + (size_t)head * 768 * 64;
    dst = WqkvT + (size_t)proj * 589824 + (size_t)head * 64 * 768;
    P = 768; Q = 64;
  } else if (t < 576) {
    int u = t - 432; tp = u / 12; tq = u - tp * 12;
    src = wo; dst = WoT; P = 768; Q = 768;
  } else if (t < 1152) {
    int u = t - 576; tp = u / 48; tq = u - tp * 48;
    src = w1; dst = W1T; P = 768; Q = 3072;
  } else {
    int u = t - 1152; tp = u / 12; tq = u - tp * 12;
    src = w2; dst = W2T; P = 3072; Q = 768;
  }
  int j = tid & 63, i0 = tid >> 6;
#pragma unroll
  for (int i = i0; i < 64; i += 4)
    T[i][j] = src[(size_t)(tp * 64 + i) * Q + tq * 64 + j];
  __syncthreads();
#pragma unroll
  for (int i = i0; i < 64; i += 4)
    dst[(size_t)(tq * 64 + i) * P + tp * 64 + j] = (bf16_t)T[j][i];
}

// ---------------- LayerNorm over D=768, one token per block (LN2) ----------------
__global__ __launch_bounds__(256) void k_layernorm(const float* __restrict__ x,
                                                   const float* __restrict__ g,
                                                   const float* __restrict__ bb,
                                                   bf16_t* __restrict__ out) {
  int t = blockIdx.x, tid = threadIdx.x;
  const float* xr = x + (size_t)t * Dn;
  float v0 = xr[tid], v1 = xr[tid + 256], v2 = xr[tid + 512];
  float s = v0 + v1 + v2;
  float ss = v0 * v0 + v1 * v1 + v2 * v2;
  __shared__ float red[8];
#pragma unroll
  for (int off = 32; off > 0; off >>= 1) {
    s += __shfl_down(s, off);
    ss += __shfl_down(ss, off);
  }
  int w = tid >> 6, l = tid & 63;
  if (l == 0) { red[w] = s; red[4 + w] = ss; }
  __syncthreads();
  s = red[0] + red[1] + red[2] + red[3];
  ss = red[4] + red[5] + red[6] + red[7];
  float mu = s * (1.0f / Dn);
  float var = ss * (1.0f / Dn) - mu * mu;
  float rstd = rsqrtf(var + 1e-5f);
  bf16_t* orow = out + (size_t)t * Dn;
  orow[tid]       = (bf16_t)((v0 - mu) * rstd * g[tid]       + bb[tid]);
  orow[tid + 256] = (bf16_t)((v1 - mu) * rstd * g[tid + 256] + bb[tid + 256]);
  orow[tid + 512] = (bf16_t)((v2 - mu) * rstd * g[tid + 512] + bb[tid + 512]);
}

// ---------------- bf16 MFMA GEMM, gl_lds16 staging, BK in {32,64} as stacked halves ----------------
// R11 lesson: BK=128 (and any config with >1 resident pass) regresses — keep BK<=64,
// single pass (grid <= OCC*256), OCC>=3 where LDS permits.
enum { EPI_QK = 0, EPI_VT = 1, EPI_Y = 2, EPI_GELU = 3, EPI_OUT = 4 };

template <int MT, int NT, int BK, int EPI, int OCC, int SWZ>
__global__ __launch_bounds__(256, OCC) void k_gemm(const bf16_t* __restrict__ A,
                                                   const bf16_t* __restrict__ Bt,
                                                   int N, int K,
                                                   const float* __restrict__ bias,
                                                   const float* __restrict__ resid,
                                                   void* __restrict__ out0,
                                                   void* __restrict__ out1) {
  constexpr int MI = MT / 32, NI = NT / 32;
  constexpr int WROWS = MT / 2, WCOLS = NT / 2;
  constexpr int KS = BK / 32;                 // MFMA k-steps (= LDS halves) per round
  __shared__ __align__(16) bf16_t As[2][MT * BK];
  __shared__ __align__(16) bf16_t Bs[2][NT * BK];
  const int tid = threadIdx.x;
  const int w = tid >> 6, l = tid & 63;
  const int wm = w >> 1, wn = w & 1;
  const int mloc = l & 15, kblk = l >> 4;
  int bx = blockIdx.x, by = blockIdx.y;
  if constexpr (SWZ) {  // requires gridDim.y % 8 == 0
    int lin = by * gridDim.x + bx;
    int xcd = lin & 7, s = lin >> 3;
    by = xcd * (gridDim.y >> 3) + s / gridDim.x;
    bx = s - (s / gridDim.x) * gridDim.x;
  }

  f32x4 acc[MI][NI];
#pragma unroll
  for (int i = 0; i < MI; ++i)
#pragma unroll
    for (int j = 0; j < NI; ++j) acc[i][j] = f32x4{0.f, 0.f, 0.f, 0.f};

  const bf16_t* gA = A + (size_t)(by * MT + (tid >> 2)) * K + (tid & 3) * 8;
  const bf16_t* gB = Bt + (size_t)(bx * NT + (tid >> 2)) * K + (tid & 3) * 8;
  const int nk = K / BK;

  auto stage = [&](int kt, int buf) {
#pragma unroll
    for (int h = 0; h < KS; ++h) {
#pragma unroll
      for (int rb = 0; rb < MT / 64; ++rb)
        gl_lds16(gA + (size_t)rb * 64 * K + kt * BK + h * 32,
                 (char*)&As[buf][0] + h * (MT * 64) + rb * 4096 + w * 1024);
#pragma unroll
      for (int rb = 0; rb < NT / 64; ++rb)
        gl_lds16(gB + (size_t)rb * 64 * K + kt * BK + h * 32,
                 (char*)&Bs[buf][0] + h * (NT * 64) + rb * 4096 + w * 1024);
    }
  };

  stage(0, 0);
  for (int kt = 0; kt < nk; ++kt) {
    __syncthreads();
    if (kt + 1 < nk) stage(kt + 1, (kt + 1) & 1);
    const bf16_t* Ab = &As[kt & 1][0];
    const bf16_t* Bb = &Bs[kt & 1][0];
    bf16x8 af[MI][KS], bfv[NI][KS];
#pragma unroll
    for (int mi = 0; mi < MI; ++mi)
#pragma unroll
      for (int ks = 0; ks < KS; ++ks)
        af[mi][ks] = *(const bf16x8*)&Ab[ks * (MT * 32) + (wm * WROWS + mi * 16 + mloc) * 32 + kblk * 8];
#pragma unroll
    for (int ni = 0; ni < NI; ++ni)
#pragma unroll
      for (int ks = 0; ks < KS; ++ks)
        bfv[ni][ks] = *(const bf16x8*)&Bb[ks * (NT * 32) + (wn * WCOLS + ni * 16 + mloc) * 32 + kblk * 8];
#pragma unroll
    for (int ks = 0; ks < KS; ++ks)
#pragma unroll
      for (int mi = 0; mi < MI; ++mi)
#pragma unroll
        for (int ni = 0; ni < NI; ++ni)
          acc[mi][ni] = MFMA_B16(af[mi][ks], bfv[ni][ks], acc[mi][ni]);
  }

  const int gmb = by * MT + wm * WROWS + kblk * 4;
  const int gnb = bx * NT + wn * WCOLS + mloc;
  if constexpr (EPI == EPI_QK) {
    constexpr int TPP = 768 / NT;  // n-tiles per projection
    const int proj = bx / TPP;     // 0 = Q (scaled), 1 = K
#pragma unroll
    for (int mi = 0; mi < MI; ++mi)
#pragma unroll
      for (int ni = 0; ni < NI; ++ni) {
        int gn = gnb + ni * 16;
        float bv = bias[gn];
        int gm0 = gmb + mi * 16;
        if (proj == 0) {
          bf16_t* dst = (bf16_t*)out0;
#pragma unroll
          for (int r = 0; r < 4; ++r)
            dst[(size_t)(gm0 + r) * 768 + gn] = (bf16_t)((acc[mi][ni][r] + bv) * QSCALE);
        } else {
          bf16_t* dst = (bf16_t*)out1;
#pragma unroll
          for (int r = 0; r < 4; ++r)
            dst[(size_t)(gm0 + r) * 768 + (gn - 768)] = (bf16_t)(acc[mi][ni][r] + bv);
        }
      }
  } else if constexpr (EPI == EPI_VT) {
    bf16_t* dst = (bf16_t*)out0;
#pragma unroll
    for (int mi = 0; mi < MI; ++mi)
#pragma unroll
      for (int ni = 0; ni < NI; ++ni) {
        int gn = gnb + ni * 16;
        int bq = gn >> 11, sq = gn & 2047;
#pragma unroll
        for (int r = 0; r < 4; ++r) {
          int gm = gmb + mi * 16 + r;
          int hq = gm >> 6, dk = gm & 63;
          dst[((size_t)(bq * Hn + hq) * 64 + dk) * Sn + sq] = (bf16_t)(acc[mi][ni][r] + bias[gm]);
        }
      }
  } else if constexpr (EPI == EPI_GELU) {
    bf16_t* dst = (bf16_t*)out0;
#pragma unroll
    for (int mi = 0; mi < MI; ++mi)
#pragma unroll
      for (int ni = 0; ni < NI; ++ni) {
        int gn = gnb + ni * 16;
        float bv = bias[gn];
#pragma unroll
        for (int r = 0; r < 4; ++r) {
          int gm = gmb + mi * 16 + r;
          float t = acc[mi][ni][r] + bv;
          float ge = 0.5f * t * (1.0f + erff(t * 0.70710678118654752f));
          dst[(size_t)gm * N + gn] = (bf16_t)ge;
        }
      }
  } else {  // EPI_Y / EPI_OUT: + bias + residual, fp32 out
    float* dst = (float*)out0;
#pragma unroll
    for (int mi = 0; mi < MI; ++mi)
#pragma unroll
      for (int ni = 0; ni < NI; ++ni) {
        int gn = gnb + ni * 16;
        float bv = bias[gn];
#pragma unroll
        for (int r = 0; r < 4; ++r) {
          int gm = gmb + mi * 16 + r;
          dst[(size_t)gm * N + gn] = acc[mi][ni][r] + bv + resid[(size_t)gm * N + gn];
        }
      }
  }
}

// ---------------- flash attention: 512 threads, 2 kv-groups x 4 q-waves ----------------
// R12 evidence: attn has 1536 waves chip-wide (1.5/SIMD) — occupancy-starved with
// LDS/MFMA floors ~15µs vs 42 measured. Fix: kv-parallel groups. Group g (waves
// 4g..4g+3) processes 64-kv tiles g, g+2, ... Fixed-max softmax makes partials
// ADDITIVE (O_unnorm, l sum across groups) -> combine is one LDS round-trip.
// 2 q-subtiles/wave kept (each K/V fragment feeds 2 MFMAs). 3072 waves total.
__global__ __launch_bounds__(512, 2) void k_attn(const bf16_t* __restrict__ Q,
                                                 const bf16_t* __restrict__ K,
                                                 const bf16_t* __restrict__ VT,
                                                 bf16_t* __restrict__ O) {
  // [0,32K): Ks per group (2 bufs x 8KB); [32K,64K): Vs per group (2 bufs x 8KB).
  // After the last barrier the whole array is reused as the f32 combine buffer.
  __shared__ __align__(16) char smem[65536];
  const int tid = threadIdx.x, w = tid >> 6, l = tid & 63;
  const int g = w >> 2, lw = w & 3;
  const int mloc = l & 15, kblk = l >> 4;
  const int bh = blockIdx.y, b = bh / Hn, h = bh - b * Hn;
  const int q0 = blockIdx.x * 128;

  // two q-subtiles per wave: qa = q0 + lw*32 + mloc, qb = qa + 16
  const size_t qoffA = (size_t)(b * Sn + q0 + lw * 32 + mloc) * Dn + h * 64 + kblk * 8;
  const bf16x8 qfa0 = *(const bf16x8*)(Q + qoffA);
  const bf16x8 qfa1 = *(const bf16x8*)(Q + qoffA + 32);
  const bf16x8 qfb0 = *(const bf16x8*)(Q + qoffA + (size_t)16 * Dn);
  const bf16x8 qfb1 = *(const bf16x8*)(Q + qoffA + (size_t)16 * Dn + 32);

  bf16x8 ones;
#pragma unroll
  for (int j = 0; j < 8; ++j) ones[j] = (bf16_t)1.0f;

  // K staging: lane covers σ-row tq = lw*16 + (l>>2) of the 64-row tile
  const int tq = lw * 16 + (l >> 2);
  const int s0 = (tq & 0x23) | ((tq & 0x0C) << 1) | ((tq & 0x10) >> 2);
  const bf16_t* Kg = K + (size_t)(b * Sn + s0) * Dn + h * 64 + (l & 3) * 8;
  // V staging: calls j=0,1 -> code = lw*2+j: chunk c = code>>2, dk-rowgrp rg = code&3
  const int c0 = (2 * lw) >> 2, rg0 = (2 * lw) & 3;
  const int c1 = (2 * lw + 1) >> 2, rg1 = (2 * lw + 1) & 3;
  const bf16_t* Vg0 = VT + ((size_t)bh * 64 + rg0 * 16 + (l >> 2)) * Sn + c0 * 32 + (l & 3) * 8;
  const bf16_t* Vg1 = VT + ((size_t)bh * 64 + rg1 * 16 + (l >> 2)) * Sn + c1 * 32 + (l & 3) * 8;

  char* Kbase = smem + g * 16384;          // 2 bufs x 8192 B
  char* Vbase = smem + 32768 + g * 16384;  // 2 bufs x 8192 B

  f32x4 lacca = f32x4{0.f, 0.f, 0.f, 0.f};
  f32x4 laccb = f32x4{0.f, 0.f, 0.f, 0.f};
  f32x4 oacca[4], oaccb[4];
#pragma unroll
  for (int md = 0; md < 4; ++md) {
    oacca[md] = f32x4{0.f, 0.f, 0.f, 0.f};
    oaccb[md] = f32x4{0.f, 0.f, 0.f, 0.f};
  }

  auto stage = [&](int tile, int buf) {   // tile = 64-kv tile index
    const size_t kv0 = (size_t)tile * 64;
    gl_lds16(Kg + kv0 * Dn,      Kbase + buf * 8192 + lw * 1024);
    gl_lds16(Kg + kv0 * Dn + 32, Kbase + buf * 8192 + 4096 + lw * 1024);
    gl_lds16(Vg0 + kv0, Vbase + buf * 8192 + c0 * 4096 + rg0 * 1024);
    gl_lds16(Vg1 + kv0, Vbase + buf * 8192 + c1 * 4096 + rg1 * 1024);
  };

  constexpr int NIT = Sn / 128;  // 16 tiles per group (stride-2 over 32 tiles)
  stage(g, 0);
  for (int ii = 0; ii < NIT; ++ii) {
    __syncthreads();
    if (ii + 1 < NIT) stage(g + 2 * (ii + 1), (ii + 1) & 1);
    const bf16_t* Kb = (const bf16_t*)(Kbase + (ii & 1) * 8192);
    const bf16_t* Vb = (const bf16_t*)(Vbase + (ii & 1) * 8192);

    // S^T: 4 tiles of (16 kv x 16 q) per q-subtile; K frags read once, used twice
    f32x4 sa[4], sb[4];
#pragma unroll
    for (int ns = 0; ns < 4; ++ns) {
      const bf16x8 k0 = *(const bf16x8*)&Kb[(ns * 16 + mloc) * 32 + kblk * 8];
      const bf16x8 k1 = *(const bf16x8*)&Kb[2048 + (ns * 16 + mloc) * 32 + kblk * 8];
      f32x4 a = f32x4{0.f, 0.f, 0.f, 0.f};
      a = MFMA_B16(k0, qfa0, a);
      a = MFMA_B16(k1, qfa1, a);
      sa[ns] = a;
      f32x4 c = f32x4{0.f, 0.f, 0.f, 0.f};
      c = MFMA_B16(k0, qfb0, c);
      c = MFMA_B16(k1, qfb1, c);
      sb[ns] = c;
    }

    // P = exp2(S^T); P^T B-fragments from own registers (σ alignment, 64-row form)
    bf16x8 pa[2], pbv[2];
#pragma unroll
    for (int ns = 0; ns < 4; ++ns)
#pragma unroll
      for (int r = 0; r < 4; ++r) {
        pa[ns >> 1][(ns & 1) * 4 + r]  = (bf16_t)__builtin_amdgcn_exp2f(sa[ns][r]);
        pbv[ns >> 1][(ns & 1) * 4 + r] = (bf16_t)__builtin_amdgcn_exp2f(sb[ns][r]);
      }

#pragma unroll
    for (int c = 0; c < 2; ++c) {
      lacca = MFMA_B16(ones, pa[c], lacca);
      laccb = MFMA_B16(ones, pbv[c], laccb);
    }

    // O^T += V^T · P^T; V frags read once, used twice
#pragma unroll
    for (int md = 0; md < 4; ++md)
#pragma unroll
      for (int c = 0; c < 2; ++c) {
        const bf16x8 v = *(const bf16x8*)&Vb[c * 2048 + (md * 16 + mloc) * 32 + kblk * 8];
        oacca[md] = MFMA_B16(v, pa[c], oacca[md]);
        oaccb[md] = MFMA_B16(v, pbv[c], oaccb[md]);
      }
  }

  // ---- cross-group combine: partials are additive (fixed-max softmax) ----
  __syncthreads();                 // all compute done; smem free for reuse
  float* Red = (float*)smem;       // [lw*64+l][34]: 16 Oa + 16 Ob + la + lb
  float* p = Red + (size_t)(lw * 64 + l) * 34;
  if (g == 1) {
#pragma unroll
    for (int md = 0; md < 4; ++md)
#pragma unroll
      for (int r = 0; r < 4; ++r) {
        p[md * 4 + r]      = oacca[md][r];
        p[16 + md * 4 + r] = oaccb[md][r];
      }
    p[32] = lacca[0];
    p[33] = laccb[0];
  }
  __syncthreads();
  if (g == 0) {
#pragma unroll
    for (int md = 0; md < 4; ++md)
#pragma unroll
      for (int r = 0; r < 4; ++r) {
        oacca[md][r] += p[md * 4 + r];
        oaccb[md][r] += p[16 + md * 4 + r];
      }
    const float invA = 1.0f / (lacca[0] + p[32]);
    const float invB = 1.0f / (laccb[0] + p[33]);
    const size_t obA = (size_t)(b * Sn + q0 + lw * 32 + mloc) * Dn + h * 64 + kblk * 4;
    const size_t obB = obA + (size_t)16 * Dn;
#pragma unroll
    for (int md = 0; md < 4; ++md) {
      bf16x4 oa, ob;
#pragma unroll
      for (int r = 0; r < 4; ++r) {
        oa[r] = (bf16_t)(oacca[md][r] * invA);
        ob[r] = (bf16_t)(oaccb[md][r] * invB);
      }
      *(bf16x4*)&O[obA + md * 16] = oa;
      *(bf16x4*)&O[obB + md * 16] = ob;
    }
  }
}

// ---------------- host launch ----------------
extern "C" void kernel_launch(void* const* d_in, const int* in_sizes, int n_in,
                              void* d_out, int out_size, void* d_ws, size_t ws_size,
                              hipStream_t stream) {
  (void)in_sizes; (void)n_in; (void)out_size; (void)ws_size;
  const float* x    = (const float*)d_in[0];
  const float* wq_w = (const float*)d_in[1];
  const float* wq_b = (const float*)d_in[2];
  const float* wk_w = (const float*)d_in[3];
  const float* wk_b = (const float*)d_in[4];
  const float* wv_w = (const float*)d_in[5];
  const float* wv_b = (const float*)d_in[6];
  const float* wo_w = (const float*)d_in[7];
  const float* wo_b = (const float*)d_in[8];
  const float* ln_g = (const float*)d_in[9];
  const float* ln_b = (const float*)d_in[10];
  const float* w1   = (const float*)d_in[11];
  const float* b1   = (const float*)d_in[12];
  const float* w2   = (const float*)d_in[13];
  const float* b2   = (const float*)d_in[14];

  char* ws = (char*)d_ws;
  size_t o = 0;
  bf16_t* WqkvT = (bf16_t*)(ws + o); o += (size_t)2304 * 768 * 2;
  bf16_t* WoT   = (bf16_t*)(ws + o); o += (size_t)768 * 768 * 2;
  bf16_t* W1T   = (bf16_t*)(ws + o); o += (size_t)3072 * 768 * 2;
  bf16_t* W2T   = (bf16_t*)(ws + o); o += (size_t)768 * 3072 * 2;
  float*  QKVB  = (float*)(ws + o);  o += (size_t)2304 * 4;
  bf16_t* Hbuf  = (bf16_t*)(ws + o); o += (size_t)NTOK * 768 * 2;  // h, later reused as o
  bf16_t* Qb    = (bf16_t*)(ws + o); o += (size_t)NTOK * 768 * 2;
  bf16_t* Kb    = (bf16_t*)(ws + o); o += (size_t)NTOK * 768 * 2;
  bf16_t* VbT   = (bf16_t*)(ws + o); o += (size_t)NTOK * 768 * 2;  // [b*12+h][64][2048]
  float*  Ybuf  = (float*)(ws + o);  o += (size_t)NTOK * 768 * 4;
  bf16_t* Zbuf  = (bf16_t*)(ws + o); o += (size_t)NTOK * 768 * 2;
  bf16_t* Ubuf  = (bf16_t*)(ws + o); o += (size_t)NTOK * 3072 * 2;

  // --- weight prep + LN1 fused ---
  k_prep<<<1729 + NTOK, 256, 0, stream>>>(wq_w, wk_w, wv_w, wo_w, w1, w2,
                                          wq_b, wk_b, wv_b, WqkvT, WoT, W1T, W2T, QKVB,
                                          x, ln_g, ln_b, Hbuf);

  // --- Q,K projection (Q pre-scaled): 128x64 BK=64, 768 blocks single pass ---
  k_gemm<128, 64, 64, EPI_QK, 3, 1><<<dim3(24, 32), 256, 0, stream>>>(Hbuf, WqkvT, 1536, 768,
                                                                      QKVB, nullptr, Qb, Kb);

  // --- V^T projection: A = Wv^T [768 x 768], B = Hbuf -> VbT coalesced ---
  k_gemm<64, 64, 64, EPI_VT, 4, 0><<<dim3(64, 12), 256, 0, stream>>>(WqkvT + (size_t)2 * 589824, Hbuf,
                                                                     4096, 768, QKVB + 1536, nullptr,
                                                                     VbT, nullptr);

  // --- attention -> o (reuses Hbuf): 384 blocks x 8 waves, kv-split groups ---
  k_attn<<<dim3(Sn / 128, Bn * Hn), 512, 0, stream>>>(Qb, Kb, VbT, Hbuf);

  // --- y = o @ Wo + wo_b + x ---
  k_gemm<64, 64, 64, EPI_Y, 4, 1><<<dim3(12, 64), 256, 0, stream>>>(Hbuf, WoT, 768, 768,
                                                                    wo_b, x, Ybuf, nullptr);

  // --- LN2 -> z ---
  k_layernorm<<<NTOK, 256, 0, stream>>>(Ybuf, ln_g, ln_b, Zbuf);

  // --- FFN1 + exact GELU -> u ---
  k_gemm<128, 128, 32, EPI_GELU, 3, 1><<<dim3(24, 32), 256, 0, stream>>>(Zbuf, W1T, 3072, 768,
                                                                         b1, nullptr, Ubuf, nullptr);

  // --- FFN2 + b2 + y -> out ---
  k_gemm<64, 64, 64, EPI_OUT, 4, 1><<<dim3(12, 64), 256, 0, stream>>>(Ubuf, W2T, 768, 3072,
                                                                      b2, Ybuf, d_out, nullptr);
}